// Round 4
// baseline (610.256 us; speedup 1.0000x reference)
//
#include <hip/hip_runtime.h>
#include <hip/hip_bf16.h>
#include <math.h>

// Problem constants
constexpr int cB = 4, cT = 256, cS = 400, cD = 512, cV = 50000, cNX = 50;
constexpr int cVEXT = cV + cNX;           // 50050
constexpr int cPAN  = (cV + 127) / 128;   // 391 col panels
constexpr int cCBLD = cVEXT * 2;          // 100100 ushorts = bytes of one fp32 out row / 2

typedef __attribute__((ext_vector_type(8))) short short8v;   // 8 bf16 = 4 VGPR
typedef __attribute__((ext_vector_type(4))) float floatx4;

__device__ inline ushort f2bf(float f) {
    union { float f; unsigned u; } v; v.f = f;
    unsigned r = (v.u + 0x7FFFu + ((v.u >> 16) & 1u)) >> 16;
    return (ushort)r;
}
__device__ inline float bf2f(ushort u) {
    union { unsigned u; float f; } v; v.u = ((unsigned)u) << 16;
    return v.f;
}

// ---------------------------------------------------------------------------
// fp32 -> bf16 cast (x only, 1 MB)
// ---------------------------------------------------------------------------
__global__ __launch_bounds__(256) void cast_kernel(
    const float* __restrict__ src, ushort* __restrict__ dst, int n4)
{
    const int stride = gridDim.x * 256;
    for (int i = blockIdx.x * 256 + threadIdx.x; i < n4; i += stride) {
        float4 v = *(const float4*)(src + (size_t)i * 4);
        ushort4 o;
        o.x = f2bf(v.x); o.y = f2bf(v.y); o.z = f2bf(v.z); o.w = f2bf(v.w);
        *(ushort4*)(dst + (size_t)i * 4) = o;
    }
}

// ---------------------------------------------------------------------------
// W-resident bf16 MFMA GEMM.
// Grid (cPAN, 2). Block = 512 thr = 8 waves (2M x 4N). LDS: W panel
// (128 cols x 512 K bf16, XOR-swizzled) + double-buffered A tile (128x32).
// Each block computes 512 rows x 128 cols of logits, writes bf16 logits
// in-slot into d_out (row stride cCBLD ushorts) + per-(row,panel) softmax
// partials (pm, ps).
// ---------------------------------------------------------------------------
__global__ __launch_bounds__(512) void gemm_wres(
    const ushort* __restrict__ A, const float* __restrict__ W32,
    const float* __restrict__ bias, ushort* __restrict__ Cb,
    float* __restrict__ pm, float* __restrict__ ps)
{
    __shared__ ushort Ws[128 * cD];       // 131072 B, swizzled [col][k]
    __shared__ ushort As[2][128 * 32];    // 2 x 8192 B
    __shared__ float sm_m[4][128];
    __shared__ float sm_s[4][128];

    const int tid  = threadIdx.x;
    const int lane = tid & 63;
    const int wv   = tid >> 6;          // 0..7
    const int wm   = wv >> 2;           // 0..1 (64-row half of 128-row mt tile)
    const int wn   = wv & 3;            // 0..3 (32-col quarter)
    const int bn   = blockIdx.x * 128;
    const int bm0  = blockIdx.y * 512;

    // ---- stage W panel: fp32 -> bf16, chunk XOR-swizzle (p = c ^ (col&7)) ----
    for (int c = 0; c < 16; ++c) {
        const int col  = wv * 16 + c;
        int gcol = bn + col;
        if (gcol >= cV) gcol = cV - 1;    // junk cols, masked in epilogue
        const float* src = W32 + (size_t)gcol * cD + lane * 8;
        const float4 v0 = *(const float4*)src;
        const float4 v1 = *(const float4*)(src + 4);
        short8v sv;
        sv[0] = (short)f2bf(v0.x); sv[1] = (short)f2bf(v0.y);
        sv[2] = (short)f2bf(v0.z); sv[3] = (short)f2bf(v0.w);
        sv[4] = (short)f2bf(v1.x); sv[5] = (short)f2bf(v1.y);
        sv[6] = (short)f2bf(v1.z); sv[7] = (short)f2bf(v1.w);
        const int p = (lane & 56) | ((lane & 7) ^ (col & 7));
        *(short8v*)&Ws[col * cD + p * 8] = sv;
    }

    // ---- first A tile (mt=0, k0=0) ----
    {
        const int row = wv * 16 + (lane >> 2);
        const ushort* gp = A + (size_t)(bm0 + row) * cD + (lane & 3) * 8;
        __builtin_amdgcn_global_load_lds(
            (const __attribute__((address_space(1))) void*)gp,
            (__attribute__((address_space(3))) void*)&As[0][wv * 512], 16, 0, 0);
    }
    __syncthreads();

    const int fr = lane & 15;
    const int g  = lane >> 4;
    int buf = 0;

    for (int mt = 0; mt < 4; ++mt) {
        floatx4 acc[4][2] = {};
        for (int ks = 0; ks < 16; ++ks) {
            // prefetch next A tile into the other buffer
            int nmt = mt, nks = ks + 1;
            if (nks == 16) { nks = 0; ++nmt; }
            if (nmt < 4) {
                const int row = wv * 16 + (lane >> 2);
                const ushort* gp = A + (size_t)(bm0 + nmt * 128 + row) * cD
                                     + nks * 32 + (lane & 3) * 8;
                __builtin_amdgcn_global_load_lds(
                    (const __attribute__((address_space(1))) void*)gp,
                    (__attribute__((address_space(3))) void*)&As[buf ^ 1][wv * 512], 16, 0, 0);
            }
            // compute current k-step
            const int k0 = ks * 32;
            short8v a[4], b[2];
            #pragma unroll
            for (int mi = 0; mi < 4; ++mi)
                a[mi] = *(const short8v*)&As[buf][(wm * 64 + mi * 16 + fr) * 32 + g * 8];
            const int cch = (k0 >> 3) + g;                       // logical chunk
            const int pch = (cch & 56) | ((cch & 7) ^ (fr & 7)); // swizzled
            #pragma unroll
            for (int ni = 0; ni < 2; ++ni) {
                const int col = wn * 32 + ni * 16 + fr;
                b[ni] = *(const short8v*)&Ws[col * cD + pch * 8];
            }
            #pragma unroll
            for (int mi = 0; mi < 4; ++mi)
                #pragma unroll
                for (int ni = 0; ni < 2; ++ni)
                    acc[mi][ni] = __builtin_amdgcn_mfma_f32_16x16x32_bf16(
                        a[mi], b[ni], acc[mi][ni], 0, 0, 0);
            __syncthreads();
            buf ^= 1;
        }

        // ---- epilogue for this mt: bias, row stats, bf16 store ----
        float bv[2]; bool val[2];
        #pragma unroll
        for (int ni = 0; ni < 2; ++ni) {
            const int colg = bn + wn * 32 + ni * 16 + fr;
            val[ni] = colg < cV;
            bv[ni] = val[ni] ? bias[colg] : 0.f;
        }
        #pragma unroll
        for (int mi = 0; mi < 4; ++mi)
            #pragma unroll
            for (int ni = 0; ni < 2; ++ni)
                #pragma unroll
                for (int r = 0; r < 4; ++r)
                    acc[mi][ni][r] += bv[ni];

        #pragma unroll
        for (int mi = 0; mi < 4; ++mi) {
            #pragma unroll
            for (int r = 0; r < 4; ++r) {
                float mx = -1e30f;
                #pragma unroll
                for (int ni = 0; ni < 2; ++ni)
                    if (val[ni]) mx = fmaxf(mx, acc[mi][ni][r]);
                #pragma unroll
                for (int sw = 1; sw < 16; sw <<= 1)
                    mx = fmaxf(mx, __shfl_xor(mx, sw));
                float sm = 0.f;
                #pragma unroll
                for (int ni = 0; ni < 2; ++ni)
                    if (val[ni]) sm += __expf(acc[mi][ni][r] - mx);
                #pragma unroll
                for (int sw = 1; sw < 16; sw <<= 1)
                    sm += __shfl_xor(sm, sw);
                if (fr == 0) {
                    const int rl = wm * 64 + mi * 16 + g * 4 + r;
                    sm_m[wn][rl] = mx;
                    sm_s[wn][rl] = sm;
                }
            }
        }
        __syncthreads();
        if (tid < 128) {
            float m = sm_m[0][tid], s = sm_s[0][tid];
            #pragma unroll
            for (int i = 1; i < 4; ++i) {
                const float m2 = sm_m[i][tid], s2 = sm_s[i][tid];
                const float nm = fmaxf(m, m2);
                s = s * __expf(m - nm) + s2 * __expf(m2 - nm);
                m = nm;
            }
            const int grow = bm0 + mt * 128 + tid;
            pm[(size_t)grow * cPAN + blockIdx.x] = m;
            ps[(size_t)grow * cPAN + blockIdx.x] = s;
        }
        // bf16 logits, in-slot (junk cols >= cV land in unused slot space)
        #pragma unroll
        for (int mi = 0; mi < 4; ++mi) {
            #pragma unroll
            for (int ni = 0; ni < 2; ++ni) {
                const int colg = bn + wn * 32 + ni * 16 + fr;
                #pragma unroll
                for (int r = 0; r < 4; ++r) {
                    const int row = bm0 + mt * 128 + wm * 64 + mi * 16 + g * 4 + r;
                    Cb[(size_t)row * cCBLD + colg] = f2bf(acc[mi][ni][r]);
                }
            }
        }
    }
}

// ---------------------------------------------------------------------------
// combine partials -> rowadd = log(pgen) - m - log(s)
// ---------------------------------------------------------------------------
__global__ __launch_bounds__(256) void combine_kernel(
    const float* __restrict__ pm, const float* __restrict__ ps,
    const float* __restrict__ pgen, float* __restrict__ rowadd)
{
    const int row = blockIdx.x;
    const int tid = threadIdx.x;
    float m = -1e30f, s = 0.f;
    for (int i = tid; i < cPAN; i += 256) {
        const float mi = pm[(size_t)row * cPAN + i];
        const float si = ps[(size_t)row * cPAN + i];
        const float nm = fmaxf(m, mi);
        s = s * __expf(m - nm) + si * __expf(mi - nm);
        m = nm;
    }
    #pragma unroll
    for (int sw = 1; sw < 64; sw <<= 1) {
        const float mo = __shfl_xor(m, sw);
        const float so = __shfl_xor(s, sw);
        const float nm = fmaxf(m, mo);
        s = s * __expf(m - nm) + so * __expf(mo - nm);
        m = nm;
    }
    __shared__ float rm[4], rs[4];
    if ((tid & 63) == 0) { rm[tid >> 6] = m; rs[tid >> 6] = s; }
    __syncthreads();
    if (tid == 0) {
        m = rm[0]; s = rs[0];
        #pragma unroll
        for (int i = 1; i < 4; ++i) {
            const float nm = fmaxf(m, rm[i]);
            s = s * __expf(m - nm) + rs[i] * __expf(rm[i] - nm);
            m = nm;
        }
        rowadd[row] = __logf(pgen[row]) - m - __logf(s);
    }
}

// ---------------------------------------------------------------------------
// affine transform, in-place per row: stage bf16 row in LDS, then
// out[v] = v<V ? max(l + rowadd, LOGMIN) : LOGMIN. One block per row.
// ---------------------------------------------------------------------------
__global__ __launch_bounds__(512) void transform_kernel(
    float* __restrict__ out, const float* __restrict__ rowadd)
{
    __shared__ ushort rowbuf[cPAN * 128];   // 50048 ushorts = 100096 B
    const int row = blockIdx.x;
    const int tid = threadIdx.x;
    const float a = rowadd[row];
    constexpr float LOGMIN = -20.72326583694641f;   // log(1e-9)
    const ushort4* src = (const ushort4*)((const ushort*)out + (size_t)row * cCBLD);
    for (int i = tid; i < (cPAN * 128) / 4; i += 512)
        ((ushort4*)rowbuf)[i] = src[i];
    __syncthreads();
    float2* dst = (float2*)(out + (size_t)row * cVEXT);
    for (int i = tid; i < cVEXT / 2; i += 512) {
        const int v = i * 2;
        float2 o;
        o.x = (v     < cV) ? fmaxf(bf2f(rowbuf[v])     + a, LOGMIN) : LOGMIN;
        o.y = (v + 1 < cV) ? fmaxf(bf2f(rowbuf[v + 1]) + a, LOGMIN) : LOGMIN;
        dst[i] = o;
    }
}

// ---------------------------------------------------------------------------
// scatter fixup in log space: out[row,p] = log(exp(out[row,p]) + sum_adds(p))
// ---------------------------------------------------------------------------
__global__ __launch_bounds__(256) void fixup_kernel(
    float* __restrict__ out, const int* __restrict__ ebev,
    const float* __restrict__ attn)
{
    const int row = blockIdx.x;
    const int b = row / cT;
    __shared__ int pos[cS];
    __shared__ float add[cS];
    for (int s = threadIdx.x; s < cS; s += 256) {
        pos[s] = ebev[b * cS + s];
        add[s] = attn[(size_t)row * cS + s];
    }
    __syncthreads();
    for (int s = threadIdx.x; s < cS; s += 256) {
        const int p = pos[s];
        bool leader = true;
        for (int s2 = 0; s2 < s; ++s2)
            if (pos[s2] == p) { leader = false; break; }
        if (!leader) continue;
        float sum = add[s];
        for (int s2 = s + 1; s2 < cS; ++s2)
            if (pos[s2] == p) sum += add[s2];
        const size_t off = (size_t)row * cVEXT + p;
        out[off] = __logf(__expf(out[off]) + sum);
    }
}

// ---------------------------------------------------------------------------
// Tiled fp32 GEMM (small projections)
// ---------------------------------------------------------------------------
__global__ __launch_bounds__(256) void gemm_bt(
    const float* __restrict__ A, const float* __restrict__ W,
    const float* __restrict__ bias, float* __restrict__ C,
    int M, int N, int K, int ldc)
{
    __shared__ __align__(16) float As[16][68];
    __shared__ __align__(16) float Bs[16][68];

    const int tid = threadIdx.x;
    const int tx = tid & 15;
    const int ty = tid >> 4;
    const int bm = blockIdx.y * 64;
    const int bn = blockIdx.x * 64;

    const int lrow = tid >> 2;
    const int lk4  = (tid & 3) * 4;

    float acc[4][4] = {};

    for (int k0 = 0; k0 < K; k0 += 16) {
        {
            int row = bm + lrow;
            float4 v = make_float4(0.f, 0.f, 0.f, 0.f);
            if (row < M) v = *(const float4*)(A + (size_t)row * K + k0 + lk4);
            As[lk4 + 0][lrow] = v.x; As[lk4 + 1][lrow] = v.y;
            As[lk4 + 2][lrow] = v.z; As[lk4 + 3][lrow] = v.w;
        }
        {
            int col = bn + lrow;
            float4 v = make_float4(0.f, 0.f, 0.f, 0.f);
            if (col < N) v = *(const float4*)(W + (size_t)col * K + k0 + lk4);
            Bs[lk4 + 0][lrow] = v.x; Bs[lk4 + 1][lrow] = v.y;
            Bs[lk4 + 2][lrow] = v.z; Bs[lk4 + 3][lrow] = v.w;
        }
        __syncthreads();

        #pragma unroll
        for (int kk = 0; kk < 16; ++kk) {
            float4 av = *(const float4*)&As[kk][ty * 4];
            float4 bv = *(const float4*)&Bs[kk][tx * 4];
            float a_[4] = {av.x, av.y, av.z, av.w};
            float b_[4] = {bv.x, bv.y, bv.z, bv.w};
            #pragma unroll
            for (int i = 0; i < 4; ++i)
                #pragma unroll
                for (int j = 0; j < 4; ++j)
                    acc[i][j] += a_[i] * b_[j];
        }
        __syncthreads();
    }

    #pragma unroll
    for (int i = 0; i < 4; ++i) {
        int row = bm + ty * 4 + i;
        if (row >= M) continue;
        #pragma unroll
        for (int j = 0; j < 4; ++j) {
            int col = bn + tx * 4 + j;
            if (col < N) {
                float b = bias ? bias[col] : 0.f;
                C[(size_t)row * ldc + col] = acc[i][j] + b;
            }
        }
    }
}

// ---------------------------------------------------------------------------
// p_gen = sigmoid(x . pgen_w + pgen_b)
// ---------------------------------------------------------------------------
__global__ __launch_bounds__(64) void pgen_kernel(
    const float* __restrict__ x, const float* __restrict__ w,
    const float* __restrict__ b, float* __restrict__ pgen)
{
    const int row = blockIdx.x;
    const int lane = threadIdx.x;
    const float* xr = x + (size_t)row * cD;
    float s = 0.f;
    for (int i = lane; i < cD; i += 64) s += xr[i] * w[i];
    #pragma unroll
    for (int off = 32; off; off >>= 1) s += __shfl_down(s, off);
    if (lane == 0) pgen[row] = 1.f / (1.f + __expf(-(s + b[0])));
}

// ---------------------------------------------------------------------------
// attention distribution (scaled by 1-pgen)
// ---------------------------------------------------------------------------
__global__ __launch_bounds__(256) void attn_kernel(
    const float* __restrict__ q, const float* __restrict__ k,
    const int* __restrict__ src_mask, const float* __restrict__ pgen,
    float* __restrict__ attn)
{
    constexpr float scale = 0.04419417382415922f;  // 1/sqrt(512)
    const int row = blockIdx.x;      // b*T + t
    const int b = row / cT;
    const int tid = threadIdx.x;

    __shared__ __align__(16) float qs[cD];
    __shared__ float sc[cS];
    __shared__ float red[4];

    for (int i = tid; i < cD; i += 256) qs[i] = q[(size_t)row * cD + i];
    __syncthreads();

    for (int s = tid; s < cS; s += 256) {
        const float* kr = k + ((size_t)b * cS + s) * cD;
        float dot = 0.f;
        #pragma unroll 4
        for (int i = 0; i < cD; i += 4) {
            float4 kv = *(const float4*)(kr + i);
            dot += qs[i] * kv.x + qs[i + 1] * kv.y + qs[i + 2] * kv.z + qs[i + 3] * kv.w;
        }
        float v = dot * scale;
        if (src_mask[b * cS + s] == 0) v = -1e9f;
        sc[s] = v;
    }
    __syncthreads();

    float m = -3.4e38f;
    for (int s = tid; s < cS; s += 256) m = fmaxf(m, sc[s]);
    #pragma unroll
    for (int off = 32; off; off >>= 1) m = fmaxf(m, __shfl_down(m, off));
    if ((tid & 63) == 0) red[tid >> 6] = m;
    __syncthreads();
    m = fmaxf(fmaxf(red[0], red[1]), fmaxf(red[2], red[3]));
    __syncthreads();

    float sum = 0.f;
    for (int s = tid; s < cS; s += 256) {
        float e = __expf(sc[s] - m);
        sc[s] = e;
        sum += e;
    }
    #pragma unroll
    for (int off = 32; off; off >>= 1) sum += __shfl_down(sum, off);
    if ((tid & 63) == 0) red[tid >> 6] = sum;
    __syncthreads();
    sum = red[0] + red[1] + red[2] + red[3];

    const float w = (1.f - pgen[row]) / sum;
    for (int s = tid; s < cS; s += 256)
        attn[(size_t)row * cS + s] = sc[s] * w;
}

extern "C" void kernel_launch(void* const* d_in, const int* in_sizes, int n_in,
                              void* d_out, int out_size, void* d_ws, size_t ws_size,
                              hipStream_t stream)
{
    const float* x      = (const float*)d_in[0];   // (B,T,D)
    const float* enc    = (const float*)d_in[1];   // (B,S,D)
    const int*   mask   = (const int*)d_in[2];     // (B,1,S)
    const int*   ebev   = (const int*)d_in[3];     // (B,S)
    const float* fc_w   = (const float*)d_in[5];   // (V,D)
    const float* fc_b   = (const float*)d_in[6];   // (V,)
    const float* pgen_w = (const float*)d_in[7];   // (1,D)
    const float* pgen_b = (const float*)d_in[8];   // (1,)
    const float* wq     = (const float*)d_in[9];   // (D,D)
    const float* bq     = (const float*)d_in[10];  // (D,)
    const float* wk     = (const float*)d_in[11];  // (D,D)
    const float* bk     = (const float*)d_in[12];  // (D,)
    float* out = (float*)d_out;

    float* ws     = (float*)d_ws;
    float* q      = ws;                               // B*T*D
    float* kbuf   = q + (size_t)cB * cT * cD;         // B*S*D
    float* pgen   = kbuf + (size_t)cB * cS * cD;      // B*T
    float* attn   = pgen + cB * cT;                   // B*T*S
    float* rowadd = attn + (size_t)cB * cT * cS;      // B*T
    float* pm     = rowadd + cB * cT;                 // B*T*cPAN
    float* ps     = pm + (size_t)cB * cT * cPAN;      // B*T*cPAN
    ushort* xb    = (ushort*)(ps + (size_t)cB * cT * cPAN);   // B*T*D bf16

    const dim3 blk(256);
    const int MQ = cB * cT;    // 1024
    const int MK = cB * cS;    // 1600

    // bf16 cast of x (for MFMA A-staging)
    cast_kernel<<<dim3(512), blk, 0, stream>>>(x, xb, (cB * cT * cD) / 4);

    // projections (fp32)
    gemm_bt<<<dim3(cD / 64, MQ / 64), blk, 0, stream>>>(x, wq, bq, q, MQ, cD, cD, cD);
    gemm_bt<<<dim3(cD / 64, MK / 64), blk, 0, stream>>>(enc, wk, bk, kbuf, MK, cD, cD, cD);
    pgen_kernel<<<dim3(MQ), dim3(64), 0, stream>>>(x, pgen_w, pgen_b, pgen);

    // attention distribution
    attn_kernel<<<dim3(MQ), blk, 0, stream>>>(q, kbuf, mask, pgen, attn);

    // W-resident logits GEMM: bf16 logits in-slot in d_out + softmax partials
    gemm_wres<<<dim3(cPAN, 2), dim3(512), 0, stream>>>(
        xb, fc_w, fc_b, (ushort*)out, pm, ps);

    // combine partials -> rowadd = log(pgen) - m - log(s)
    combine_kernel<<<dim3(MQ), blk, 0, stream>>>(pm, ps, pgen, rowadd);

    // affine transform + clamp (in-place expand bf16 -> fp32 log-probs)
    transform_kernel<<<dim3(MQ), dim3(512), 0, stream>>>(out, rowadd);

    // scatter fixup in log space
    fixup_kernel<<<dim3(MQ), blk, 0, stream>>>(out, ebev, attn);
}

// Round 5
// 506.512 us; speedup vs baseline: 1.2048x; 1.2048x over previous
//
#include <hip/hip_runtime.h>
#include <hip/hip_bf16.h>
#include <math.h>

// Problem constants
constexpr int cB = 4, cT = 256, cS = 400, cD = 512, cV = 50000, cNX = 50;
constexpr int cVEXT = cV + cNX;           // 50050
constexpr int cPAN  = (cV + 127) / 128;   // 391 col panels of the big GEMM
constexpr int cCBLD = cVEXT * 2;          // ushort stride of one fp32 out row

typedef __attribute__((ext_vector_type(8))) short short8v;   // 8 bf16
typedef __attribute__((ext_vector_type(4))) float floatx4;

__device__ inline ushort f2bf(float f) {
    union { float f; unsigned u; } v; v.f = f;
    unsigned r = (v.u + 0x7FFFu + ((v.u >> 16) & 1u)) >> 16;
    return (ushort)r;
}
__device__ inline float bf2f(ushort u) {
    union { unsigned u; float f; } v; v.u = ((unsigned)u) << 16;
    return v.f;
}

// ---------------------------------------------------------------------------
// fp32 -> bf16 cast
// ---------------------------------------------------------------------------
__global__ __launch_bounds__(256) void cast_kernel(
    const float* __restrict__ src, ushort* __restrict__ dst, int n4)
{
    const int stride = gridDim.x * 256;
    for (int i = blockIdx.x * 256 + threadIdx.x; i < n4; i += stride) {
        float4 v = *(const float4*)(src + (size_t)i * 4);
        ushort4 o;
        o.x = f2bf(v.x); o.y = f2bf(v.y); o.z = f2bf(v.z); o.w = f2bf(v.w);
        *(ushort4*)(dst + (size_t)i * 4) = o;
    }
}

// ---------------------------------------------------------------------------
// bf16 MFMA GEMM, 128x128 tile, BK=32, 4 waves (2x2), A+B double-buffered,
// one barrier per K-step (stage t+1 issued before compute t).
// Grid: x = row-block (fast-varying -> consecutive blocks share the W panel),
//       y = col panel.
// STATS=true : writes bf16 C in-slot (stride cCBLD) + per-(row,panel) softmax
//              partials pm/ps.  STATS=false: fp32 C with bias, stride ldc.
// ---------------------------------------------------------------------------
template<bool STATS>
__global__ __launch_bounds__(256) void gemm2(
    const ushort* __restrict__ A, const ushort* __restrict__ Wb,
    const float* __restrict__ bias,
    float* __restrict__ Cf, ushort* __restrict__ Cb,
    float* __restrict__ pm, float* __restrict__ ps,
    int M, int N, int K, int ldc)
{
    __shared__ ushort As[2][128 * 32];
    __shared__ ushort Bs[2][128 * 32];
    __shared__ float sm_m[2][128];
    __shared__ float sm_s[2][128];

    const int tid  = threadIdx.x;
    const int lane = tid & 63;
    const int wv   = tid >> 6;
    const int wm   = wv >> 1;
    const int wn   = wv & 1;
    const int bm   = blockIdx.x * 128;
    const int bn   = blockIdx.y * 128;

    const int srow = lane >> 2;        // 0..15
    const int sk   = (lane & 3) * 8;   // bf16 elems

    const int nt = K >> 5;

    floatx4 acc[4][4] = {};

    auto stage = [&](int bidx, int t) {
        const int k0 = t * 32;
        #pragma unroll
        for (int c = 0; c < 2; ++c) {
            const int lr = wv * 32 + c * 16;
            int ga = bm + lr + srow; if (ga >= M) ga = M - 1;
            __builtin_amdgcn_global_load_lds(
                (const __attribute__((address_space(1))) void*)(A + (size_t)ga * K + k0 + sk),
                (__attribute__((address_space(3))) void*)&As[bidx][lr * 32], 16, 0, 0);
        }
        #pragma unroll
        for (int c = 0; c < 2; ++c) {
            const int lr = wv * 32 + c * 16;
            int gb = bn + lr + srow; if (gb >= N) gb = N - 1;
            __builtin_amdgcn_global_load_lds(
                (const __attribute__((address_space(1))) void*)(Wb + (size_t)gb * K + k0 + sk),
                (__attribute__((address_space(3))) void*)&Bs[bidx][lr * 32], 16, 0, 0);
        }
    };

    stage(0, 0);
    __syncthreads();

    const int fr = lane & 15;
    const int g  = lane >> 4;
    int buf = 0;

    for (int t = 0; t < nt; ++t) {
        if (t + 1 < nt) stage(buf ^ 1, t + 1);
        short8v a[4], b[4];
        #pragma unroll
        for (int mi = 0; mi < 4; ++mi)
            a[mi] = *(const short8v*)&As[buf][(wm * 64 + mi * 16 + fr) * 32 + g * 8];
        #pragma unroll
        for (int ni = 0; ni < 4; ++ni)
            b[ni] = *(const short8v*)&Bs[buf][(wn * 64 + ni * 16 + fr) * 32 + g * 8];
        #pragma unroll
        for (int mi = 0; mi < 4; ++mi)
            #pragma unroll
            for (int ni = 0; ni < 4; ++ni)
                acc[mi][ni] = __builtin_amdgcn_mfma_f32_16x16x32_bf16(
                    a[mi], b[ni], acc[mi][ni], 0, 0, 0);
        __syncthreads();
        buf ^= 1;
    }

    // ---- epilogue ----
    float bv[4]; bool val[4];
    #pragma unroll
    for (int ni = 0; ni < 4; ++ni) {
        const int colg = bn + wn * 64 + ni * 16 + fr;
        val[ni] = (colg < N);
        bv[ni] = val[ni] ? bias[colg] : 0.f;
    }
    #pragma unroll
    for (int mi = 0; mi < 4; ++mi)
        #pragma unroll
        for (int ni = 0; ni < 4; ++ni)
            #pragma unroll
            for (int r = 0; r < 4; ++r)
                acc[mi][ni][r] += bv[ni];

    if constexpr (STATS) {
        // per-(mi,r) row stats over this wave's 64 cols
        #pragma unroll
        for (int mi = 0; mi < 4; ++mi) {
            #pragma unroll
            for (int r = 0; r < 4; ++r) {
                float mx = -1e30f;
                #pragma unroll
                for (int ni = 0; ni < 4; ++ni)
                    if (val[ni]) mx = fmaxf(mx, acc[mi][ni][r]);
                #pragma unroll
                for (int sw = 1; sw < 16; sw <<= 1)
                    mx = fmaxf(mx, __shfl_xor(mx, sw));
                float sm = 0.f;
                #pragma unroll
                for (int ni = 0; ni < 4; ++ni)
                    if (val[ni]) sm += __expf(acc[mi][ni][r] - mx);
                #pragma unroll
                for (int sw = 1; sw < 16; sw <<= 1)
                    sm += __shfl_xor(sm, sw);
                if (fr == 0) {
                    const int rl = wm * 64 + mi * 16 + g * 4 + r;
                    sm_m[wn][rl] = mx;
                    sm_s[wn][rl] = sm;
                }
            }
        }
        __syncthreads();
        if (tid < 128) {
            const float m0 = sm_m[0][tid], m1 = sm_m[1][tid];
            const float s0 = sm_s[0][tid], s1 = sm_s[1][tid];
            const float mm = fmaxf(m0, m1);
            const float ss = s0 * __expf(m0 - mm) + s1 * __expf(m1 - mm);
            const int grow = bm + tid;
            if (grow < M) {
                pm[(size_t)grow * cPAN + blockIdx.y] = mm;
                ps[(size_t)grow * cPAN + blockIdx.y] = ss;
            }
        }
        // bf16 logits in-slot
        #pragma unroll
        for (int mi = 0; mi < 4; ++mi) {
            #pragma unroll
            for (int ni = 0; ni < 4; ++ni) {
                if (!val[ni]) continue;
                const int colg = bn + wn * 64 + ni * 16 + fr;
                #pragma unroll
                for (int r = 0; r < 4; ++r) {
                    const int row = bm + wm * 64 + mi * 16 + g * 4 + r;
                    if (row < M) Cb[(size_t)row * cCBLD + colg] = f2bf(acc[mi][ni][r]);
                }
            }
        }
    } else {
        #pragma unroll
        for (int mi = 0; mi < 4; ++mi) {
            #pragma unroll
            for (int ni = 0; ni < 4; ++ni) {
                if (!val[ni]) continue;
                const int colg = bn + wn * 64 + ni * 16 + fr;
                #pragma unroll
                for (int r = 0; r < 4; ++r) {
                    const int row = bm + wm * 64 + mi * 16 + g * 4 + r;
                    if (row < M) Cf[(size_t)row * ldc + colg] = acc[mi][ni][r];
                }
            }
        }
    }
}

// ---------------------------------------------------------------------------
// fused combine + affine-log transform + scatter fixup. One block (512) / row.
// wave 0: online-merge the 391 (m,s) partials -> a = log(pgen) - m - log(s)
// waves 1..7: stage bf16 logits row + scatter indices/adds into LDS
// then: stream out[v] = max(l+a, LOGMIN) (fp32, in-place expand),
// then: leaders rewrite scatter positions with log(max(exp(l+a)+sum, 1e-9)).
// ---------------------------------------------------------------------------
__global__ __launch_bounds__(512) void transform_fused(
    float* __restrict__ out, const float* __restrict__ pm,
    const float* __restrict__ ps, const float* __restrict__ pgen,
    const int* __restrict__ ebev, const float* __restrict__ attn)
{
    __shared__ ushort rowbuf[cPAN * 128];   // 100096 B
    __shared__ float sA;
    __shared__ int   pos[cS];
    __shared__ float add[cS];

    const int row = blockIdx.x;
    const int b   = row / cT;
    const int tid = threadIdx.x;
    constexpr float LOGMIN = -20.72326583694641f;   // log(1e-9)

    if (tid < 64) {
        float m = -1e30f, s = 0.f;
        for (int i = tid; i < cPAN; i += 64) {
            const float mi = pm[(size_t)row * cPAN + i];
            const float si = ps[(size_t)row * cPAN + i];
            const float nm = fmaxf(m, mi);
            s = s * __expf(m - nm) + si * __expf(mi - nm);
            m = nm;
        }
        #pragma unroll
        for (int sw = 1; sw < 64; sw <<= 1) {
            const float mo = __shfl_xor(m, sw);
            const float so = __shfl_xor(s, sw);
            const float nm = fmaxf(m, mo);
            s = s * __expf(m - nm) + so * __expf(mo - nm);
            m = nm;
        }
        if (tid == 0) sA = __logf(pgen[row]) - m - __logf(s);
    } else {
        const int t = tid - 64;   // 0..447
        const ushort4* src = (const ushort4*)((const ushort*)out + (size_t)row * cCBLD);
        for (int i = t; i < (cPAN * 128) / 4; i += 448)
            ((ushort4*)rowbuf)[i] = src[i];
        for (int s = t; s < cS; s += 448) {
            pos[s] = ebev[b * cS + s];
            add[s] = attn[(size_t)row * cS + s];
        }
    }
    __syncthreads();
    const float a = sA;

    // streaming affine + clamp (bf16 -> fp32, in place)
    float2* dst = (float2*)(out + (size_t)row * cVEXT);
    for (int i = tid; i < cVEXT / 2; i += 512) {
        const int v = i * 2;
        float2 o;
        o.x = (v     < cV) ? fmaxf(bf2f(rowbuf[v])     + a, LOGMIN) : LOGMIN;
        o.y = (v + 1 < cV) ? fmaxf(bf2f(rowbuf[v + 1]) + a, LOGMIN) : LOGMIN;
        dst[i] = o;
    }
    __syncthreads();

    // scatter fixup (exact reference semantics)
    for (int s = tid; s < cS; s += 512) {
        const int p = pos[s];
        bool leader = true;
        for (int s2 = 0; s2 < s; ++s2)
            if (pos[s2] == p) { leader = false; break; }
        if (!leader) continue;
        float sum = add[s];
        for (int s2 = s + 1; s2 < cS; ++s2)
            if (pos[s2] == p) sum += add[s2];
        const float base = (p < cV) ? __expf(bf2f(rowbuf[p]) + a) : 0.f;
        out[(size_t)row * cVEXT + p] = __logf(fmaxf(base + sum, 1e-9f));
    }
}

// ---------------------------------------------------------------------------
// p_gen = sigmoid(x . pgen_w + pgen_b)
// ---------------------------------------------------------------------------
__global__ __launch_bounds__(64) void pgen_kernel(
    const float* __restrict__ x, const float* __restrict__ w,
    const float* __restrict__ b, float* __restrict__ pgen)
{
    const int row = blockIdx.x;
    const int lane = threadIdx.x;
    const float* xr = x + (size_t)row * cD;
    float s = 0.f;
    for (int i = lane; i < cD; i += 64) s += xr[i] * w[i];
    #pragma unroll
    for (int off = 32; off; off >>= 1) s += __shfl_down(s, off);
    if (lane == 0) pgen[row] = 1.f / (1.f + __expf(-(s + b[0])));
}

// ---------------------------------------------------------------------------
// attention distribution (scaled by 1-pgen)
// ---------------------------------------------------------------------------
__global__ __launch_bounds__(256) void attn_kernel(
    const float* __restrict__ q, const float* __restrict__ k,
    const int* __restrict__ src_mask, const float* __restrict__ pgen,
    float* __restrict__ attn)
{
    constexpr float scale = 0.04419417382415922f;  // 1/sqrt(512)
    const int row = blockIdx.x;      // b*T + t
    const int b = row / cT;
    const int tid = threadIdx.x;

    __shared__ __align__(16) float qs[cD];
    __shared__ float sc[cS];
    __shared__ float red[4];

    for (int i = tid; i < cD; i += 256) qs[i] = q[(size_t)row * cD + i];
    __syncthreads();

    for (int s = tid; s < cS; s += 256) {
        const float* kr = k + ((size_t)b * cS + s) * cD;
        float dot = 0.f;
        #pragma unroll 4
        for (int i = 0; i < cD; i += 4) {
            float4 kv = *(const float4*)(kr + i);
            float4 qv = *(const float4*)(qs + i);
            dot += qv.x * kv.x + qv.y * kv.y + qv.z * kv.z + qv.w * kv.w;
        }
        float v = dot * scale;
        if (src_mask[b * cS + s] == 0) v = -1e9f;
        sc[s] = v;
    }
    __syncthreads();

    float m = -3.4e38f;
    for (int s = tid; s < cS; s += 256) m = fmaxf(m, sc[s]);
    #pragma unroll
    for (int off = 32; off; off >>= 1) m = fmaxf(m, __shfl_down(m, off));
    if ((tid & 63) == 0) red[tid >> 6] = m;
    __syncthreads();
    m = fmaxf(fmaxf(red[0], red[1]), fmaxf(red[2], red[3]));
    __syncthreads();

    float sum = 0.f;
    for (int s = tid; s < cS; s += 256) {
        float e = __expf(sc[s] - m);
        sc[s] = e;
        sum += e;
    }
    #pragma unroll
    for (int off = 32; off; off >>= 1) sum += __shfl_down(sum, off);
    if ((tid & 63) == 0) red[tid >> 6] = sum;
    __syncthreads();
    sum = red[0] + red[1] + red[2] + red[3];

    const float w = (1.f - pgen[row]) / sum;
    for (int s = tid; s < cS; s += 256)
        attn[(size_t)row * cS + s] = sc[s] * w;
}

extern "C" void kernel_launch(void* const* d_in, const int* in_sizes, int n_in,
                              void* d_out, int out_size, void* d_ws, size_t ws_size,
                              hipStream_t stream)
{
    const float* x      = (const float*)d_in[0];   // (B,T,D)
    const float* enc    = (const float*)d_in[1];   // (B,S,D)
    const int*   mask   = (const int*)d_in[2];     // (B,1,S)
    const int*   ebev   = (const int*)d_in[3];     // (B,S)
    const float* fc_w   = (const float*)d_in[5];   // (V,D)
    const float* fc_b   = (const float*)d_in[6];   // (V,)
    const float* pgen_w = (const float*)d_in[7];   // (1,D)
    const float* pgen_b = (const float*)d_in[8];   // (1,)
    const float* wq     = (const float*)d_in[9];   // (D,D)
    const float* bq     = (const float*)d_in[10];  // (D,)
    const float* wk     = (const float*)d_in[11];  // (D,D)
    const float* bk     = (const float*)d_in[12];  // (D,)
    float* out = (float*)d_out;

    // workspace layout (floats first, then bf16)
    float* ws     = (float*)d_ws;
    float* q      = ws;                                   // 1024*512
    float* kbuf   = q + (size_t)cB * cT * cD;             // 1600*512
    float* pgen   = kbuf + (size_t)cB * cS * cD;          // 1024
    float* attn   = pgen + cB * cT;                       // 1024*400
    float* pm     = attn + (size_t)cB * cT * cS;          // 1024*391
    float* ps     = pm + (size_t)cB * cT * cPAN;          // 1024*391
    ushort* xb    = (ushort*)(ps + (size_t)cB * cT * cPAN);
    ushort* encb  = xb + (size_t)cB * cT * cD;
    ushort* wqb   = encb + (size_t)cB * cS * cD;
    ushort* wkb   = wqb + (size_t)cD * cD;
    ushort* wb    = wkb + (size_t)cD * cD;                // V*D bf16 (51 MB)

    const dim3 blk(256);
    const int MQ = cB * cT;    // 1024
    const int MK = cB * cS;    // 1600

    // casts
    cast_kernel<<<dim3(512), blk, 0, stream>>>(x, xb, (cB * cT * cD) / 4);
    cast_kernel<<<dim3(512), blk, 0, stream>>>(enc, encb, (cB * cS * cD) / 4);
    cast_kernel<<<dim3(256), blk, 0, stream>>>(wq, wqb, (cD * cD) / 4);
    cast_kernel<<<dim3(256), blk, 0, stream>>>(wk, wkb, (cD * cD) / 4);
    cast_kernel<<<dim3(2048), blk, 0, stream>>>(fc_w, wb, (cV * cD) / 4);

    // projections (bf16 MFMA, fp32 out)
    gemm2<false><<<dim3(MQ / 128, cD / 128), blk, 0, stream>>>(
        xb, wqb, bq, q, nullptr, nullptr, nullptr, MQ, cD, cD, cD);
    gemm2<false><<<dim3((MK + 127) / 128, cD / 128), blk, 0, stream>>>(
        encb, wkb, bk, kbuf, nullptr, nullptr, nullptr, MK, cD, cD, cD);
    pgen_kernel<<<dim3(MQ), dim3(64), 0, stream>>>(x, pgen_w, pgen_b, pgen);

    // attention distribution
    attn_kernel<<<dim3(MQ), blk, 0, stream>>>(q, kbuf, mask, pgen, attn);

    // big logits GEMM: bf16 C in-slot + softmax partials
    gemm2<true><<<dim3(MQ / 128, cPAN), blk, 0, stream>>>(
        xb, wb, fc_b, nullptr, (ushort*)out, pm, ps, MQ, cV, cD, 0);

    // fused combine + transform + scatter fixup
    transform_fused<<<dim3(MQ), dim3(512), 0, stream>>>(
        out, pm, ps, pgen, ebev, attn);
}

// Round 6
// 413.439 us; speedup vs baseline: 1.4760x; 1.2251x over previous
//
#include <hip/hip_runtime.h>
#include <hip/hip_bf16.h>
#include <math.h>

// Problem constants
constexpr int cB = 4, cT = 256, cS = 400, cD = 512, cV = 50000, cNX = 50;
constexpr int cVEXT = cV + cNX;           // 50050
constexpr int cPAN  = (cV + 127) / 128;   // 391 col panels of the big GEMM
constexpr int cCBLD = cVEXT * 2;          // ushort stride of one fp32 out row

typedef __attribute__((ext_vector_type(8))) short short8v;   // 8 bf16
typedef __attribute__((ext_vector_type(4))) float floatx4;

__device__ inline ushort f2bf(float f) {
    union { float f; unsigned u; } v; v.f = f;
    unsigned r = (v.u + 0x7FFFu + ((v.u >> 16) & 1u)) >> 16;
    return (ushort)r;
}
__device__ inline float bf2f(ushort u) {
    union { unsigned u; float f; } v; v.u = ((unsigned)u) << 16;
    return v.f;
}

// ---------------------------------------------------------------------------
// fp32 -> bf16 cast
// ---------------------------------------------------------------------------
__global__ __launch_bounds__(256) void cast_kernel(
    const float* __restrict__ src, ushort* __restrict__ dst, int n4)
{
    const int stride = gridDim.x * 256;
    for (int i = blockIdx.x * 256 + threadIdx.x; i < n4; i += stride) {
        float4 v = *(const float4*)(src + (size_t)i * 4);
        ushort4 o;
        o.x = f2bf(v.x); o.y = f2bf(v.y); o.z = f2bf(v.z); o.w = f2bf(v.w);
        *(ushort4*)(dst + (size_t)i * 4) = o;
    }
}

// ---------------------------------------------------------------------------
// bf16 MFMA GEMM, 128x128 tile, BK=32, 4 waves (2x2), A+B double-buffered,
// one barrier per K-step (stage t+1 issued before compute t).
// Grid: x = row-block (fast-varying -> consecutive blocks share the W panel),
//       y = col panel.
// STATS=true : writes bf16 C in-slot (stride cCBLD) + per-(row,panel) softmax
//              partials pm/ps.  STATS=false: fp32 C with bias, stride ldc.
// ---------------------------------------------------------------------------
template<bool STATS>
__global__ __launch_bounds__(256) void gemm2(
    const ushort* __restrict__ A, const ushort* __restrict__ Wb,
    const float* __restrict__ bias,
    float* __restrict__ Cf, ushort* __restrict__ Cb,
    float* __restrict__ pm, float* __restrict__ ps,
    int M, int N, int K, int ldc)
{
    __shared__ ushort As[2][128 * 32];
    __shared__ ushort Bs[2][128 * 32];
    __shared__ float sm_m[2][128];
    __shared__ float sm_s[2][128];

    const int tid  = threadIdx.x;
    const int lane = tid & 63;
    const int wv   = tid >> 6;
    const int wm   = wv >> 1;
    const int wn   = wv & 1;
    const int bm   = blockIdx.x * 128;
    const int bn   = blockIdx.y * 128;

    const int srow = lane >> 2;        // 0..15
    const int sk   = (lane & 3) * 8;   // bf16 elems

    const int nt = K >> 5;

    floatx4 acc[4][4] = {};

    auto stage = [&](int bidx, int t) {
        const int k0 = t * 32;
        #pragma unroll
        for (int c = 0; c < 2; ++c) {
            const int lr = wv * 32 + c * 16;
            int ga = bm + lr + srow; if (ga >= M) ga = M - 1;
            __builtin_amdgcn_global_load_lds(
                (const __attribute__((address_space(1))) void*)(A + (size_t)ga * K + k0 + sk),
                (__attribute__((address_space(3))) void*)&As[bidx][lr * 32], 16, 0, 0);
        }
        #pragma unroll
        for (int c = 0; c < 2; ++c) {
            const int lr = wv * 32 + c * 16;
            int gb = bn + lr + srow; if (gb >= N) gb = N - 1;
            __builtin_amdgcn_global_load_lds(
                (const __attribute__((address_space(1))) void*)(Wb + (size_t)gb * K + k0 + sk),
                (__attribute__((address_space(3))) void*)&Bs[bidx][lr * 32], 16, 0, 0);
        }
    };

    stage(0, 0);
    __syncthreads();

    const int fr = lane & 15;
    const int g  = lane >> 4;
    int buf = 0;

    for (int t = 0; t < nt; ++t) {
        if (t + 1 < nt) stage(buf ^ 1, t + 1);
        short8v a[4], b[4];
        #pragma unroll
        for (int mi = 0; mi < 4; ++mi)
            a[mi] = *(const short8v*)&As[buf][(wm * 64 + mi * 16 + fr) * 32 + g * 8];
        #pragma unroll
        for (int ni = 0; ni < 4; ++ni)
            b[ni] = *(const short8v*)&Bs[buf][(wn * 64 + ni * 16 + fr) * 32 + g * 8];
        #pragma unroll
        for (int mi = 0; mi < 4; ++mi)
            #pragma unroll
            for (int ni = 0; ni < 4; ++ni)
                acc[mi][ni] = __builtin_amdgcn_mfma_f32_16x16x32_bf16(
                    a[mi], b[ni], acc[mi][ni], 0, 0, 0);
        __syncthreads();
        buf ^= 1;
    }

    // ---- epilogue ----
    float bv[4]; bool val[4];
    #pragma unroll
    for (int ni = 0; ni < 4; ++ni) {
        const int colg = bn + wn * 64 + ni * 16 + fr;
        val[ni] = (colg < N);
        bv[ni] = val[ni] ? bias[colg] : 0.f;
    }
    #pragma unroll
    for (int mi = 0; mi < 4; ++mi)
        #pragma unroll
        for (int ni = 0; ni < 4; ++ni)
            #pragma unroll
            for (int r = 0; r < 4; ++r)
                acc[mi][ni][r] += bv[ni];

    if constexpr (STATS) {
        // per-(mi,r) row stats over this wave's 64 cols
        #pragma unroll
        for (int mi = 0; mi < 4; ++mi) {
            #pragma unroll
            for (int r = 0; r < 4; ++r) {
                float mx = -1e30f;
                #pragma unroll
                for (int ni = 0; ni < 4; ++ni)
                    if (val[ni]) mx = fmaxf(mx, acc[mi][ni][r]);
                #pragma unroll
                for (int sw = 1; sw < 16; sw <<= 1)
                    mx = fmaxf(mx, __shfl_xor(mx, sw));
                float sm = 0.f;
                #pragma unroll
                for (int ni = 0; ni < 4; ++ni)
                    if (val[ni]) sm += __expf(acc[mi][ni][r] - mx);
                #pragma unroll
                for (int sw = 1; sw < 16; sw <<= 1)
                    sm += __shfl_xor(sm, sw);
                if (fr == 0) {
                    const int rl = wm * 64 + mi * 16 + g * 4 + r;
                    sm_m[wn][rl] = mx;
                    sm_s[wn][rl] = sm;
                }
            }
        }
        __syncthreads();
        if (tid < 128) {
            const float m0 = sm_m[0][tid], m1 = sm_m[1][tid];
            const float s0 = sm_s[0][tid], s1 = sm_s[1][tid];
            const float mm = fmaxf(m0, m1);
            const float ss = s0 * __expf(m0 - mm) + s1 * __expf(m1 - mm);
            const int grow = bm + tid;
            if (grow < M) {
                pm[(size_t)grow * cPAN + blockIdx.y] = mm;
                ps[(size_t)grow * cPAN + blockIdx.y] = ss;
            }
        }
        // bf16 logits in-slot
        #pragma unroll
        for (int mi = 0; mi < 4; ++mi) {
            #pragma unroll
            for (int ni = 0; ni < 4; ++ni) {
                if (!val[ni]) continue;
                const int colg = bn + wn * 64 + ni * 16 + fr;
                #pragma unroll
                for (int r = 0; r < 4; ++r) {
                    const int row = bm + wm * 64 + mi * 16 + g * 4 + r;
                    if (row < M) Cb[(size_t)row * cCBLD + colg] = f2bf(acc[mi][ni][r]);
                }
            }
        }
    } else {
        #pragma unroll
        for (int mi = 0; mi < 4; ++mi) {
            #pragma unroll
            for (int ni = 0; ni < 4; ++ni) {
                if (!val[ni]) continue;
                const int colg = bn + wn * 64 + ni * 16 + fr;
                #pragma unroll
                for (int r = 0; r < 4; ++r) {
                    const int row = bm + wm * 64 + mi * 16 + g * 4 + r;
                    if (row < M) Cf[(size_t)row * ldc + colg] = acc[mi][ni][r];
                }
            }
        }
    }
}

// ---------------------------------------------------------------------------
// combine partials -> rowadd = log(pgen) - m - log(s). One block per row.
// ---------------------------------------------------------------------------
__global__ __launch_bounds__(256) void combine_kernel(
    const float* __restrict__ pm, const float* __restrict__ ps,
    const float* __restrict__ pgen, float* __restrict__ rowadd)
{
    const int row = blockIdx.x;
    const int tid = threadIdx.x;
    float m = -1e30f, s = 0.f;
    for (int i = tid; i < cPAN; i += 256) {
        const float mi = pm[(size_t)row * cPAN + i];
        const float si = ps[(size_t)row * cPAN + i];
        const float nm = fmaxf(m, mi);
        s = s * __expf(m - nm) + si * __expf(mi - nm);
        m = nm;
    }
    #pragma unroll
    for (int sw = 1; sw < 64; sw <<= 1) {
        const float mo = __shfl_xor(m, sw);
        const float so = __shfl_xor(s, sw);
        const float nm = fmaxf(m, mo);
        s = s * __expf(m - nm) + so * __expf(mo - nm);
        m = nm;
    }
    __shared__ float rm[4], rs[4];
    if ((tid & 63) == 0) { rm[tid >> 6] = m; rs[tid >> 6] = s; }
    __syncthreads();
    if (tid == 0) {
        m = rm[0]; s = rs[0];
        #pragma unroll
        for (int i = 1; i < 4; ++i) {
            const float nm = fmaxf(m, rm[i]);
            s = s * __expf(m - nm) + rs[i] * __expf(rm[i] - nm);
            m = nm;
        }
        rowadd[row] = __logf(pgen[row]) - m - __logf(s);
    }
}

// ---------------------------------------------------------------------------
// Segmented in-place bf16->fp32 affine-log expansion + scatter fixup.
// One block (512 thr) per row. Segment [L,2L): bf16 reads = bytes [2L,4L),
// fp32 writes = bytes [4L,8L) -> disjoint; top-down order + barrier between
// segments makes the in-place expand race-free with no LDS row buffer.
// v=1, v=0 done last (v=0's 4-byte write covers v=1's read bytes).
// ---------------------------------------------------------------------------
__global__ __launch_bounds__(512) void transform_inplace(
    float* __restrict__ out, const float* __restrict__ rowadd,
    const int* __restrict__ ebev, const float* __restrict__ attn)
{
    const int row = blockIdx.x;
    const int b   = row / cT;
    const int tid = threadIdx.x;
    constexpr float LOGMIN = -20.72326583694641f;   // log(1e-9)

    __shared__ int   pos[cS];
    __shared__ float add[cS];
    for (int s = tid; s < cS; s += 512) {
        pos[s] = ebev[b * cS + s];
        add[s] = attn[(size_t)row * cS + s];
    }

    const float a = rowadd[row];
    ushort* rowu = (ushort*)out + (size_t)row * cCBLD;
    float*  rowf = out + (size_t)row * cVEXT;

    #pragma unroll 1
    for (int L = 32768; L >= 2; L >>= 1) {
        const int hi = (2 * L < cVEXT) ? 2 * L : cVEXT;
        for (int i = L + 2 * tid; i < hi; i += 1024) {
            const float x0 = bf2f(rowu[i]);
            const float x1 = bf2f(rowu[i + 1]);
            float2 o;
            o.x = (i     < cV) ? fmaxf(x0 + a, LOGMIN) : LOGMIN;
            o.y = (i + 1 < cV) ? fmaxf(x1 + a, LOGMIN) : LOGMIN;
            *(float2*)&rowf[i] = o;
        }
        __syncthreads();
    }
    if (tid == 0) {
        const float x1 = bf2f(rowu[1]);
        const float x0 = bf2f(rowu[0]);
        rowf[1] = fmaxf(x1 + a, LOGMIN);
        rowf[0] = fmaxf(x0 + a, LOGMIN);
    }
    __syncthreads();

    // scatter fixup: leaders rewrite out[row,p] = log(max(exp(l)+sum, 1e-9))
    for (int s = tid; s < cS; s += 512) {
        const int p = pos[s];
        bool leader = true;
        for (int s2 = 0; s2 < s; ++s2)
            if (pos[s2] == p) { leader = false; break; }
        if (!leader) continue;
        float sum = add[s];
        for (int s2 = s + 1; s2 < cS; ++s2)
            if (pos[s2] == p) sum += add[s2];
        const float base = __expf(rowf[p]);   // clamped; error << threshold
        rowf[p] = __logf(fmaxf(base + sum, 1e-9f));
    }
}

// ---------------------------------------------------------------------------
// p_gen = sigmoid(x . pgen_w + pgen_b)
// ---------------------------------------------------------------------------
__global__ __launch_bounds__(64) void pgen_kernel(
    const float* __restrict__ x, const float* __restrict__ w,
    const float* __restrict__ b, float* __restrict__ pgen)
{
    const int row = blockIdx.x;
    const int lane = threadIdx.x;
    const float* xr = x + (size_t)row * cD;
    float s = 0.f;
    for (int i = lane; i < cD; i += 64) s += xr[i] * w[i];
    #pragma unroll
    for (int off = 32; off; off >>= 1) s += __shfl_down(s, off);
    if (lane == 0) pgen[row] = 1.f / (1.f + __expf(-(s + b[0])));
}

// ---------------------------------------------------------------------------
// attention distribution (scaled by 1-pgen)
// ---------------------------------------------------------------------------
__global__ __launch_bounds__(256) void attn_kernel(
    const float* __restrict__ q, const float* __restrict__ k,
    const int* __restrict__ src_mask, const float* __restrict__ pgen,
    float* __restrict__ attn)
{
    constexpr float scale = 0.04419417382415922f;  // 1/sqrt(512)
    const int row = blockIdx.x;      // b*T + t
    const int b = row / cT;
    const int tid = threadIdx.x;

    __shared__ __align__(16) float qs[cD];
    __shared__ float sc[cS];
    __shared__ float red[4];

    for (int i = tid; i < cD; i += 256) qs[i] = q[(size_t)row * cD + i];
    __syncthreads();

    for (int s = tid; s < cS; s += 256) {
        const float* kr = k + ((size_t)b * cS + s) * cD;
        float dot = 0.f;
        #pragma unroll 4
        for (int i = 0; i < cD; i += 4) {
            float4 kv = *(const float4*)(kr + i);
            float4 qv = *(const float4*)(qs + i);
            dot += qv.x * kv.x + qv.y * kv.y + qv.z * kv.z + qv.w * kv.w;
        }
        float v = dot * scale;
        if (src_mask[b * cS + s] == 0) v = -1e9f;
        sc[s] = v;
    }
    __syncthreads();

    float m = -3.4e38f;
    for (int s = tid; s < cS; s += 256) m = fmaxf(m, sc[s]);
    #pragma unroll
    for (int off = 32; off; off >>= 1) m = fmaxf(m, __shfl_down(m, off));
    if ((tid & 63) == 0) red[tid >> 6] = m;
    __syncthreads();
    m = fmaxf(fmaxf(red[0], red[1]), fmaxf(red[2], red[3]));
    __syncthreads();

    float sum = 0.f;
    for (int s = tid; s < cS; s += 256) {
        float e = __expf(sc[s] - m);
        sc[s] = e;
        sum += e;
    }
    #pragma unroll
    for (int off = 32; off; off >>= 1) sum += __shfl_down(sum, off);
    if ((tid & 63) == 0) red[tid >> 6] = sum;
    __syncthreads();
    sum = red[0] + red[1] + red[2] + red[3];

    const float w = (1.f - pgen[row]) / sum;
    for (int s = tid; s < cS; s += 256)
        attn[(size_t)row * cS + s] = sc[s] * w;
}

extern "C" void kernel_launch(void* const* d_in, const int* in_sizes, int n_in,
                              void* d_out, int out_size, void* d_ws, size_t ws_size,
                              hipStream_t stream)
{
    const float* x      = (const float*)d_in[0];   // (B,T,D)
    const float* enc    = (const float*)d_in[1];   // (B,S,D)
    const int*   mask   = (const int*)d_in[2];     // (B,1,S)
    const int*   ebev   = (const int*)d_in[3];     // (B,S)
    const float* fc_w   = (const float*)d_in[5];   // (V,D)
    const float* fc_b   = (const float*)d_in[6];   // (V,)
    const float* pgen_w = (const float*)d_in[7];   // (1,D)
    const float* pgen_b = (const float*)d_in[8];   // (1,)
    const float* wq     = (const float*)d_in[9];   // (D,D)
    const float* bq     = (const float*)d_in[10];  // (D,)
    const float* wk     = (const float*)d_in[11];  // (D,D)
    const float* bk     = (const float*)d_in[12];  // (D,)
    float* out = (float*)d_out;

    // workspace layout (floats first, then bf16)
    float* ws     = (float*)d_ws;
    float* q      = ws;                                   // 1024*512
    float* kbuf   = q + (size_t)cB * cT * cD;             // 1600*512
    float* pgen   = kbuf + (size_t)cB * cS * cD;          // 1024
    float* attn   = pgen + cB * cT;                       // 1024*400
    float* pm     = attn + (size_t)cB * cT * cS;          // 1024*391
    float* ps     = pm + (size_t)cB * cT * cPAN;          // 1024*391
    float* rowadd = ps + (size_t)cB * cT * cPAN;          // 1024
    ushort* xb    = (ushort*)(rowadd + cB * cT);
    ushort* encb  = xb + (size_t)cB * cT * cD;
    ushort* wqb   = encb + (size_t)cB * cS * cD;
    ushort* wkb   = wqb + (size_t)cD * cD;
    ushort* wb    = wkb + (size_t)cD * cD;                // V*D bf16 (51 MB)

    const dim3 blk(256);
    const int MQ = cB * cT;    // 1024
    const int MK = cB * cS;    // 1600

    // casts
    cast_kernel<<<dim3(512), blk, 0, stream>>>(x, xb, (cB * cT * cD) / 4);
    cast_kernel<<<dim3(512), blk, 0, stream>>>(enc, encb, (cB * cS * cD) / 4);
    cast_kernel<<<dim3(256), blk, 0, stream>>>(wq, wqb, (cD * cD) / 4);
    cast_kernel<<<dim3(256), blk, 0, stream>>>(wk, wkb, (cD * cD) / 4);
    cast_kernel<<<dim3(2048), blk, 0, stream>>>(fc_w, wb, (cV * cD) / 4);

    // projections (bf16 MFMA, fp32 out)
    gemm2<false><<<dim3(MQ / 128, cD / 128), blk, 0, stream>>>(
        xb, wqb, bq, q, nullptr, nullptr, nullptr, MQ, cD, cD, cD);
    gemm2<false><<<dim3((MK + 127) / 128, cD / 128), blk, 0, stream>>>(
        encb, wkb, bk, kbuf, nullptr, nullptr, nullptr, MK, cD, cD, cD);
    pgen_kernel<<<dim3(MQ), dim3(64), 0, stream>>>(x, pgen_w, pgen_b, pgen);

    // attention distribution
    attn_kernel<<<dim3(MQ), blk, 0, stream>>>(q, kbuf, mask, pgen, attn);

    // big logits GEMM: bf16 C in-slot + softmax partials
    gemm2<true><<<dim3(MQ / 128, cPAN), blk, 0, stream>>>(
        xb, wb, fc_b, nullptr, (ushort*)out, pm, ps, MQ, cV, cD, 0);

    // combine partials -> rowadd
    combine_kernel<<<dim3(MQ), blk, 0, stream>>>(pm, ps, pgen, rowadd);

    // segmented in-place transform + scatter fixup
    transform_inplace<<<dim3(MQ), dim3(512), 0, stream>>>(
        out, rowadd, ebev, attn);
}